// Round 6
// baseline (356.629 us; speedup 1.0000x reference)
//
#include <hip/hip_runtime.h>
#include <hip/hip_fp16.h>
#include <cstddef>

// AffinityPropagate: per-pixel normalized 3x3 stencil, 24 steps.
// R6: T=12 x 2 identical launches (normalize in-kernel both; packed-weight
// store/load dropped — fixed ~47us harness poison makes it pure overhead).
// Thread = 1 row x 8 cols (64 rows x 8 col-groups = 512 threads). Own row is
// register-resident across steps (outputs feed next step directly); LDS only
// carries neighbor rows. Per step: 2x10-float neighbor-row reads + 2 own-edge
// reads + 8-float write, all contiguous -> ds_read2/write2_b32 (~15 DS ops vs
// R5's 38). PITCH=77 (odd): b32 banks (13r+8u)%32 collide only as 2-way = free.
//
// Tap order: w0=NW w1=N w2=NE w3=W [center] w4=E w5=SW w6=S w7=SE
//
// Ring/frontier: staged halo 13 (66x66), weight halo 12 (64x64 = staged
// rows/cols 1..64, recomputed every step; staged ring 0 frozen). After step s
// valid staged rings are [s,65-s]; after 12 steps the 40x40 tile is exact.
// Out-of-image px have all-zero weights -> stay exactly 0 = zero padding.

#define HIMG 480
#define WIMG 640
#define HW   (HIMG * WIMG)
#define BN   8

#define TILE   40
#define TSTEPS 12
#define IH     13                // staged halo
#define WHL    12                // weight halo
#define SWD    66                // staged rows/cols
#define PITCH  77                // LDS row pitch (odd -> conflict-free b32)
#define NT     512

__global__ __launch_bounds__(NT, 4) void affprop12(
    const float* __restrict__ aff,
    const float* __restrict__ src,
    float* __restrict__ dst)
{
    __shared__ float fA[SWD * PITCH];
    __shared__ float fB[SWD * PITCH];

    const int tid = threadIdx.x;
    const int ox  = blockIdx.x * TILE;
    const int oy  = blockIdx.y * TILE;
    const int b   = blockIdx.z;

    const float* __restrict__ sb = src + (size_t)b * HW;
    float*       __restrict__ db = dst + (size_t)b * HW;

    // ---- stage input region [oy-13, oy+53) x [ox-13, ox+53), 0 outside image
    for (int i = tid; i < SWD * SWD; i += NT) {
        int r  = i / SWD;
        int c  = i - r * SWD;
        int gy = oy - IH + r;
        int gx = ox - IH + c;
        float v = 0.f;
        if ((unsigned)gy < (unsigned)HIMG && (unsigned)gx < (unsigned)WIMG)
            v = sb[gy * WIMG + gx];
        fA[r * PITCH + c] = v;
    }
    // ---- zero-fill buffer B (deterministic stale rings)
    for (int i = tid; i < SWD * PITCH; i += NT)
        fB[i] = 0.f;

    // ---- per-thread: weight row r (0..63), col group u (8 px: cols 8u..8u+7)
    const int u = tid & 7;
    const int r = tid >> 3;

    // normalize weights in-kernel (affinity reads are L3-absorbed)
    __half2 wv[8][4];   // [px j][tap pair (NW,N)(NE,W)(E,SW)(S,SE)]
    float   wcc[8];     // center weights (f32)
    {
        const int gy = oy - WHL + r;
        const bool rin = (unsigned)gy < (unsigned)HIMG;
        #pragma unroll
        for (int j = 0; j < 8; ++j) {
            const int gx = ox - WHL + 8 * u + j;
            const bool in = rin && (unsigned)gx < (unsigned)WIMG;
            float w[8];
            float s = 0.f;
            if (in) {
                const float* ap = aff + (size_t)b * 8 * HW + (size_t)gy * WIMG + gx;
                #pragma unroll
                for (int k = 0; k < 8; ++k) { w[k] = ap[(size_t)k * HW]; s += fabsf(w[k]); }
            } else {
                #pragma unroll
                for (int k = 0; k < 8; ++k) w[k] = 0.f;
                s = 1.f;
            }
            float rr  = in ? 1.0f / s : 0.f;
            float acc = 0.f;
            #pragma unroll
            for (int k = 0; k < 8; ++k) { w[k] *= rr; acc += w[k]; }
            wv[j][0] = __floats2half2_rn(w[0], w[1]);
            wv[j][1] = __floats2half2_rn(w[2], w[3]);
            wv[j][2] = __floats2half2_rn(w[4], w[5]);
            wv[j][3] = __floats2half2_rn(w[6], w[7]);
            wcc[j] = in ? 1.0f - acc : 0.f;
        }
    }
    __syncthreads();

    // base LDS indices: own output row = staged row r+1; logical col window
    // covers weight cols 8u-1..8u+8 = staged cols 8u..8u+9.
    const int tbase = r * PITCH + 8 * u;            // row above (staged r)
    const int mbase = tbase + PITCH;                // own row   (staged r+1)
    const int bbase = mbase + PITCH;                // row below (staged r+2)

    // own 8 px register-resident across steps
    float v[8];
    #pragma unroll
    for (int j = 0; j < 8; ++j) v[j] = fA[mbase + 1 + j];

    const float* fin = fA;
    float*       fo  = fB;

    #pragma unroll 1
    for (int s = 0; s < TSTEPS; ++s) {
        float T[10], B[10];
        #pragma unroll
        for (int k = 0; k < 10; ++k) T[k] = fin[tbase + k];
        #pragma unroll
        for (int k = 0; k < 10; ++k) B[k] = fin[bbase + k];
        float M0 = fin[mbase];          // own-row left edge (neighbor u-1)
        float M9 = fin[mbase + 9];      // own-row right edge (neighbor u+1)

        float M[10];
        M[0] = M0;
        #pragma unroll
        for (int j = 0; j < 8; ++j) M[j + 1] = v[j];
        M[9] = M9;

        float nv[8];
        #pragma unroll
        for (int j = 0; j < 8; ++j) {
            nv[j] = wcc[j] * M[j + 1]
                + __low2float (wv[j][0]) * T[j]       // NW
                + __high2float(wv[j][0]) * T[j + 1]   // N
                + __low2float (wv[j][1]) * T[j + 2]   // NE
                + __high2float(wv[j][1]) * M[j]       // W
                + __low2float (wv[j][2]) * M[j + 2]   // E
                + __high2float(wv[j][2]) * B[j]       // SW
                + __low2float (wv[j][3]) * B[j + 1]   // S
                + __high2float(wv[j][3]) * B[j + 2];  // SE
        }

        #pragma unroll
        for (int j = 0; j < 8; ++j) v[j] = nv[j];

        if (s < TSTEPS - 1) {
            #pragma unroll
            for (int j = 0; j < 8; ++j) fo[mbase + 1 + j] = nv[j];
            __syncthreads();
            const float* t = fin; fin = fo; fo = (float*)t;
        }
    }

    // ---- store: weight rows/cols 12..51 = the 40x40 output tile
    if ((unsigned)(r - WHL) < (unsigned)TILE) {
        const int gy = oy + (r - WHL);
        #pragma unroll
        for (int j = 0; j < 8; ++j) {
            const int wcol = 8 * u + j;
            if ((unsigned)(wcol - WHL) < (unsigned)TILE)
                db[(size_t)gy * WIMG + ox + (wcol - WHL)] = v[j];
        }
    }
}

extern "C" void kernel_launch(void* const* d_in, const int* in_sizes, int n_in,
                              void* d_out, int out_size, void* d_ws, size_t ws_size,
                              hipStream_t stream)
{
    const float* aff  = (const float*)d_in[0];
    const float* feat = (const float*)d_in[1];
    float* out = (float*)d_out;
    float* ws  = (float*)d_ws;   // one [8,1,480,640] frame (9.83 MB)

    dim3 blk(NT, 1, 1);
    dim3 grd(WIMG / TILE, HIMG / TILE, BN);   // 16 x 12 x 8 = 1536 blocks

    affprop12<<<grd, blk, 0, stream>>>(aff, feat, ws);
    affprop12<<<grd, blk, 0, stream>>>(aff, ws, out);
}

// Round 7
// 233.165 us; speedup vs baseline: 1.5295x; 1.5295x over previous
//
#include <hip/hip_runtime.h>
#include <hip/hip_fp16.h>
#include <cstddef>

// AffinityPropagate: per-pixel normalized 3x3 stencil, 24 steps.
// R7: R5's proven mapping (lane = consecutive column: coalesced global loads,
// stride-1 LDS) + register-resident own column (30 DS ops/step vs 38) +
// last step computes in registers and stores straight to global (no write/
// barrier) + packed-weight store/load dropped (fixed ~47us harness poison
// makes it pure overhead; both dispatches normalize in-kernel, L3-absorbed).
// R6 lesson: row-per-lane layouts de-coalesce global loads (FETCH +73MB,
// +55us) — lane MUST map to consecutive pixels.
//
// Tap order: w0=NW w1=N w2=NE w3=W [center] w4=E w5=SW w6=S w7=SE
//
// Ring/frontier: staged halo 13 (66x66), weight halo 12 (64x64 = staged
// rows/cols 1..64, recomputed every step; staged ring 0 frozen). Ring r is
// valid at step s for s <= r; output tile = staged rings >= 13 read at step
// 12 from rings >= 12 — all valid. fB's zero ring 0 only corrupts ring 1
// from step 2 on, which is already invalid-by-design. Out-of-image px have
// all-zero weights -> stay exactly 0 = zero padding.

#define HIMG 480
#define WIMG 640
#define HW   (HIMG * WIMG)
#define BN   8

#define TILE   40
#define TSTEPS 12
#define IH     13                // staged halo
#define WHL    12                // weight halo
#define SWD    66                // staged rows/cols
#define PITCH  77                // LDS row pitch (odd -> conflict-free b32)
#define NT     512

__global__ __launch_bounds__(NT, 4) void affprop12(
    const float* __restrict__ aff,
    const float* __restrict__ src,
    float* __restrict__ dst)
{
    __shared__ float fA[SWD * PITCH];
    __shared__ float fB[SWD * PITCH];

    const int tid = threadIdx.x;
    const int ox  = blockIdx.x * TILE;
    const int oy  = blockIdx.y * TILE;
    const int b   = blockIdx.z;

    const float* __restrict__ sb = src + (size_t)b * HW;
    float*       __restrict__ db = dst + (size_t)b * HW;

    // ---- stage input region [oy-13, oy+53) x [ox-13, ox+53), 0 outside image
    for (int i = tid; i < SWD * SWD; i += NT) {
        int r  = i / SWD;
        int c  = i - r * SWD;
        int gy = oy - IH + r;
        int gx = ox - IH + c;
        float v0 = 0.f;
        if ((unsigned)gy < (unsigned)HIMG && (unsigned)gx < (unsigned)WIMG)
            v0 = sb[gy * WIMG + gx];
        fA[r * PITCH + c] = v0;
    }
    // ---- zero-fill buffer B (deterministic stale rings)
    for (int i = tid; i < SWD * PITCH; i += NT)
        fB[i] = 0.f;

    // ---- per-thread: weight col c (0..63), row group g (weight rows 8g..8g+7)
    const int c = tid & 63;
    const int g = tid >> 6;

    // normalize weights in-kernel (lane=c -> consecutive gx, coalesced;
    // redundant halo reads absorbed by L2/L3)
    __half2 wv[8][4];   // [row i][tap pair (NW,N)(NE,W)(E,SW)(S,SE)]
    float   wcc[8];     // center weights (f32)
    {
        const int gx = ox - WHL + c;
        const bool cin = (unsigned)gx < (unsigned)WIMG;
        #pragma unroll
        for (int i = 0; i < 8; ++i) {
            const int gy = oy - WHL + 8 * g + i;
            const bool in = cin && (unsigned)gy < (unsigned)HIMG;
            float w[8];
            float s = 0.f;
            if (in) {
                const float* ap = aff + (size_t)b * 8 * HW + (size_t)gy * WIMG + gx;
                #pragma unroll
                for (int k = 0; k < 8; ++k) { w[k] = ap[(size_t)k * HW]; s += fabsf(w[k]); }
            } else {
                #pragma unroll
                for (int k = 0; k < 8; ++k) w[k] = 0.f;
                s = 1.f;
            }
            float rr  = in ? 1.0f / s : 0.f;
            float acc = 0.f;
            #pragma unroll
            for (int k = 0; k < 8; ++k) { w[k] *= rr; acc += w[k]; }
            wv[i][0] = __floats2half2_rn(w[0], w[1]);
            wv[i][1] = __floats2half2_rn(w[2], w[3]);
            wv[i][2] = __floats2half2_rn(w[4], w[5]);
            wv[i][3] = __floats2half2_rn(w[6], w[7]);
            wcc[i] = in ? 1.0f - acc : 0.f;
        }
    }
    __syncthreads();

    // ---- own column register-resident: staged rows 8g+1..8g+8, staged col c+1
    const int tbase = (8 * g) * PITCH + c;    // window top row (staged 8g), left col
    float v[8];
    #pragma unroll
    for (int i = 0; i < 8; ++i) v[i] = fA[tbase + (i + 1) * PITCH + 1];

    const float* fin = fA;
    float*       fo  = fB;

    #pragma unroll 1
    for (int s = 0; s < TSTEPS; ++s) {
        // rolling 3-row window; per step: 22 b32 reads + 8 writes (none on last)
        const float* rp = fin + tbase;
        float La = rp[0], Ma = rp[1], Ra = rp[2];   // boundary row above (3 reads)
        rp += PITCH;
        float Lb = rp[0], Rb = rp[2];               // own row 0: L/R only
        float Mb = v[0];

        float nv[8];
        #pragma unroll
        for (int i = 0; i < 8; ++i) {
            rp += PITCH;
            float Lc = rp[0], Rc = rp[2];
            float Mc = (i < 7) ? v[i + 1] : rp[1];  // boundary row below center

            nv[i] = wcc[i] * Mb
                + __low2float (wv[i][0]) * La    // NW
                + __high2float(wv[i][0]) * Ma    // N
                + __low2float (wv[i][1]) * Ra    // NE
                + __high2float(wv[i][1]) * Lb    // W
                + __low2float (wv[i][2]) * Rb    // E
                + __high2float(wv[i][2]) * Lc    // SW
                + __low2float (wv[i][3]) * Mc    // S
                + __high2float(wv[i][3]) * Rc;   // SE

            La = Lb; Ma = Mb; Ra = Rb;
            Lb = Lc; Mb = Mc; Rb = Rc;
        }

        #pragma unroll
        for (int i = 0; i < 8; ++i) v[i] = nv[i];

        if (s < TSTEPS - 1) {
            float* wp = fo + tbase + PITCH + 1;
            #pragma unroll
            for (int i = 0; i < 8; ++i) { *wp = nv[i]; wp += PITCH; }
            __syncthreads();
            const float* t = fin; fin = fo; fo = (float*)t;
        }
    }

    // ---- store from registers: weight rows/cols 12..51 = 40x40 output tile
    if ((unsigned)(c - WHL) < (unsigned)TILE) {
        const int gx = ox + (c - WHL);
        #pragma unroll
        for (int i = 0; i < 8; ++i) {
            const int wrow = 8 * g + i;
            if ((unsigned)(wrow - WHL) < (unsigned)TILE)
                db[(size_t)(oy + (wrow - WHL)) * WIMG + gx] = v[i];
        }
    }
}

extern "C" void kernel_launch(void* const* d_in, const int* in_sizes, int n_in,
                              void* d_out, int out_size, void* d_ws, size_t ws_size,
                              hipStream_t stream)
{
    const float* aff  = (const float*)d_in[0];
    const float* feat = (const float*)d_in[1];
    float* out = (float*)d_out;
    float* ws  = (float*)d_ws;   // one [8,1,480,640] frame (9.83 MB)

    dim3 blk(NT, 1, 1);
    dim3 grd(WIMG / TILE, HIMG / TILE, BN);   // 16 x 12 x 8 = 1536 blocks

    affprop12<<<grd, blk, 0, stream>>>(aff, feat, ws);
    affprop12<<<grd, blk, 0, stream>>>(aff, ws, out);
}

// Round 8
// 225.523 us; speedup vs baseline: 1.5813x; 1.0339x over previous
//
#include <hip/hip_runtime.h>
#include <cstddef>

// AffinityPropagate: per-pixel normalized 3x3 stencil, 24 steps.
// R8 = R7 structure (lane = consecutive column -> coalesced global + stride-1
// LDS; register-resident own column; last step computes in registers and
// stores straight to global) with two VALU cuts:
//   1. Weights held as 9 x f32 per px (no fp16 pack/convert): stencil is pure
//      9 FMA/px-step. R7 was VALU-bound (VALUBusy 60%) with ~8 v_cvt_f32_f16
//      per px-step from the half2 weight scheme.
//   2. fB zero-fill removed: garbage in fB ring 0 reaches only ring s-1 at
//      step s (<= ring 11 at step 12), never read for the 40x40 output.
// __launch_bounds__(512) only — cap 256 VGPRs, no forced clamp (R3 lesson:
// tight caps + big per-thread state = scratch spill, WRITE_SIZE 67MB).
//
// Tap order: w0=NW w1=N w2=NE w3=W w4=center w5=E w6=SW w7=S w8=SE
//
// Ring/frontier: staged halo 13 (66x66), weight halo 12 (64x64 = staged
// rows/cols 1..64, recomputed every step; staged ring 0 frozen from stage
// time in fA, garbage in fB). Ring r valid at step s iff r >= s; output tile
// = rings >= 13 read at step 12 from rings >= 12 — all valid. Out-of-image
// px have all-zero weights -> stay exactly 0 = zero padding.

#define HIMG 480
#define WIMG 640
#define HW   (HIMG * WIMG)
#define BN   8

#define TILE   40
#define TSTEPS 12
#define IH     13                // staged halo
#define WHL    12                // weight halo
#define SWD    66                // staged rows/cols
#define PITCH  77                // LDS row pitch (odd -> conflict-free b32)
#define NT     512

__global__ __launch_bounds__(NT) void affprop12(
    const float* __restrict__ aff,
    const float* __restrict__ src,
    float* __restrict__ dst)
{
    __shared__ float fA[SWD * PITCH];
    __shared__ float fB[SWD * PITCH];

    const int tid = threadIdx.x;
    const int ox  = blockIdx.x * TILE;
    const int oy  = blockIdx.y * TILE;
    const int b   = blockIdx.z;

    const float* __restrict__ sb = src + (size_t)b * HW;
    float*       __restrict__ db = dst + (size_t)b * HW;

    // ---- stage input region [oy-13, oy+53) x [ox-13, ox+53), 0 outside image
    for (int i = tid; i < SWD * SWD; i += NT) {
        int r  = i / SWD;
        int c  = i - r * SWD;
        int gy = oy - IH + r;
        int gx = ox - IH + c;
        float v0 = 0.f;
        if ((unsigned)gy < (unsigned)HIMG && (unsigned)gx < (unsigned)WIMG)
            v0 = sb[gy * WIMG + gx];
        fA[r * PITCH + c] = v0;
    }
    // (no fB zero-fill: stale fB ring 0 garbage reaches only ring s-1 at
    //  step s — never the output rings. NaN-safe by the same containment.)

    // ---- per-thread: weight col c (0..63), row group g (weight rows 8g..8g+7)
    const int c = tid & 63;
    const int g = tid >> 6;

    // normalize weights in-kernel, keep as f32 (9 per px = 72 VGPRs);
    // lane=c -> consecutive gx, coalesced; halo re-reads absorbed by L2/L3
    float w[8][9];   // [row i][NW,N,NE,W,center,E,SW,S,SE]
    {
        const int gx = ox - WHL + c;
        const bool cin = (unsigned)gx < (unsigned)WIMG;
        #pragma unroll
        for (int i = 0; i < 8; ++i) {
            const int gy = oy - WHL + 8 * g + i;
            const bool in = cin && (unsigned)gy < (unsigned)HIMG;
            float a[8];
            float s = 0.f;
            if (in) {
                const float* ap = aff + (size_t)b * 8 * HW + (size_t)gy * WIMG + gx;
                #pragma unroll
                for (int k = 0; k < 8; ++k) { a[k] = ap[(size_t)k * HW]; s += fabsf(a[k]); }
            } else {
                #pragma unroll
                for (int k = 0; k < 8; ++k) a[k] = 0.f;
                s = 1.f;
            }
            float rr  = in ? 1.0f / s : 0.f;
            float acc = 0.f;
            #pragma unroll
            for (int k = 0; k < 8; ++k) { a[k] *= rr; acc += a[k]; }
            w[i][0] = a[0]; w[i][1] = a[1]; w[i][2] = a[2]; w[i][3] = a[3];
            w[i][4] = in ? 1.0f - acc : 0.f;
            w[i][5] = a[4]; w[i][6] = a[5]; w[i][7] = a[6]; w[i][8] = a[7];
        }
    }
    __syncthreads();

    // ---- own column register-resident: staged rows 8g+1..8g+8, staged col c+1
    const int tbase = (8 * g) * PITCH + c;    // window top row (staged 8g), left col
    float v[8];
    #pragma unroll
    for (int i = 0; i < 8; ++i) v[i] = fA[tbase + (i + 1) * PITCH + 1];

    const float* fin = fA;
    float*       fo  = fB;

    #pragma unroll 1
    for (int s = 0; s < TSTEPS; ++s) {
        // rolling 3-row window; per step: 22 b32 reads + 8 writes (none on last)
        const float* rp = fin + tbase;
        float La = rp[0], Ma = rp[1], Ra = rp[2];   // boundary row above
        rp += PITCH;
        float Lb = rp[0], Rb = rp[2];               // own row 0: L/R only
        float Mb = v[0];

        float nv[8];
        #pragma unroll
        for (int i = 0; i < 8; ++i) {
            rp += PITCH;
            float Lc = rp[0], Rc = rp[2];
            float Mc = (i < 7) ? v[i + 1] : rp[1];  // boundary row below center

            nv[i] = w[i][4] * Mb
                  + w[i][0] * La    // NW
                  + w[i][1] * Ma    // N
                  + w[i][2] * Ra    // NE
                  + w[i][3] * Lb    // W
                  + w[i][5] * Rb    // E
                  + w[i][6] * Lc    // SW
                  + w[i][7] * Mc    // S
                  + w[i][8] * Rc;   // SE

            La = Lb; Ma = Mb; Ra = Rb;
            Lb = Lc; Mb = Mc; Rb = Rc;
        }

        #pragma unroll
        for (int i = 0; i < 8; ++i) v[i] = nv[i];

        if (s < TSTEPS - 1) {
            float* wp = fo + tbase + PITCH + 1;
            #pragma unroll
            for (int i = 0; i < 8; ++i) { *wp = nv[i]; wp += PITCH; }
            __syncthreads();
            const float* t = fin; fin = fo; fo = (float*)t;
        }
    }

    // ---- store from registers: weight rows/cols 12..51 = 40x40 output tile
    if ((unsigned)(c - WHL) < (unsigned)TILE) {
        const int gx = ox + (c - WHL);
        #pragma unroll
        for (int i = 0; i < 8; ++i) {
            const int wrow = 8 * g + i;
            if ((unsigned)(wrow - WHL) < (unsigned)TILE)
                db[(size_t)(oy + (wrow - WHL)) * WIMG + gx] = v[i];
        }
    }
}

extern "C" void kernel_launch(void* const* d_in, const int* in_sizes, int n_in,
                              void* d_out, int out_size, void* d_ws, size_t ws_size,
                              hipStream_t stream)
{
    const float* aff  = (const float*)d_in[0];
    const float* feat = (const float*)d_in[1];
    float* out = (float*)d_out;
    float* ws  = (float*)d_ws;   // one [8,1,480,640] frame (9.83 MB)

    dim3 blk(NT, 1, 1);
    dim3 grd(WIMG / TILE, HIMG / TILE, BN);   // 16 x 12 x 8 = 1536 blocks

    affprop12<<<grd, blk, 0, stream>>>(aff, feat, ws);
    affprop12<<<grd, blk, 0, stream>>>(aff, ws, out);
}